// Round 1
// baseline (6913.856 us; speedup 1.0000x reference)
//
#include <hip/hip_runtime.h>
#include <hip/hip_bf16.h>

// GraphConv scatter-add SpMM: out[row[e], :] += edge_vals[e] * x[col[e], :]
// N = 500000 nodes, E = 8000000 edges, D = 64 features, fp32.
//
// Round 0 strategy: 16 lanes per edge; each lane float4-gathers 16B of
// x[col[e]] (coalesced 256B per edge) and does 4 atomicAdds into out[row[e]].
// d_out zeroed via hipMemsetAsync (graph-capture safe).

#define D_FEAT 64

__global__ __launch_bounds__(256)
void graphconv_scatter(const float* __restrict__ x,
                       const float* __restrict__ edge_vals,
                       const int* __restrict__ row,
                       const int* __restrict__ col,
                       float* __restrict__ out,
                       int n_edges) {
    int tid = blockIdx.x * blockDim.x + threadIdx.x;
    int lane16 = tid & 15;        // 16 lanes per edge, 4 floats each = 64 feats
    int e = tid >> 4;
    if (e >= n_edges) return;

    int r = row[e];
    int c = col[e];
    float v = edge_vals[e];

    const float4* xs = (const float4*)(x + (size_t)c * D_FEAT);
    float4 xv = xs[lane16];

    float* o = out + (size_t)r * D_FEAT + lane16 * 4;
    atomicAdd(o + 0, v * xv.x);
    atomicAdd(o + 1, v * xv.y);
    atomicAdd(o + 2, v * xv.z);
    atomicAdd(o + 3, v * xv.w);
}

extern "C" void kernel_launch(void* const* d_in, const int* in_sizes, int n_in,
                              void* d_out, int out_size, void* d_ws, size_t ws_size,
                              hipStream_t stream) {
    const float* x         = (const float*)d_in[0];
    const float* edge_vals = (const float*)d_in[1];
    const int*   row       = (const int*)d_in[2];
    const int*   col       = (const int*)d_in[3];
    float* out = (float*)d_out;

    int n_edges = in_sizes[1];

    // out is poisoned 0xAA before every timed call — zero it.
    hipMemsetAsync(d_out, 0, (size_t)out_size * sizeof(float), stream);

    // 16 lanes per edge -> total threads = n_edges * 16
    long long total_threads = (long long)n_edges * 16;
    int block = 256;
    int grid = (int)((total_threads + block - 1) / block);

    graphconv_scatter<<<grid, block, 0, stream>>>(x, edge_vals, row, col, out, n_edges);
}

// Round 2
// 1395.866 us; speedup vs baseline: 4.9531x; 4.9531x over previous
//
#include <hip/hip_runtime.h>
#include <hip/hip_bf16.h>

// GraphConv SpMM: out[row[e], :] += edge_vals[e] * x[col[e], :]
// N = 500000, E = 8000000, D = 64, fp32.
//
// Round 2: build CSR per call (counting sort by row), then row-stationary
// reduce with plain float4 stores. Replaces 512M f32 device atomics
// (8.2 GB HBM RMW traffic, 6.9 ms) with 16M int atomics + dense streaming.

#define D_FEAT 64
#define SCAN_BLOCK 256
#define SCAN_ITEMS 8
#define SCAN_TILE (SCAN_BLOCK * SCAN_ITEMS)   // 2048 elements per block

// ---------------- histogram ----------------
__global__ __launch_bounds__(256)
void hist_kernel(const int* __restrict__ row, int* __restrict__ counts, int n_edges) {
    int e = blockIdx.x * blockDim.x + threadIdx.x;
    if (e < n_edges) {
        // counts[r+1] so that inclusive scan yields row starts directly
        atomicAdd(&counts[row[e] + 1], 1);
    }
}

// ---------------- 3-phase inclusive scan ----------------
__global__ __launch_bounds__(SCAN_BLOCK)
void scan1_kernel(int* __restrict__ data, int n, int* __restrict__ block_sums) {
    __shared__ int sdata[SCAN_BLOCK];
    int base = blockIdx.x * SCAN_TILE + threadIdx.x * SCAN_ITEMS;
    int vals[SCAN_ITEMS];
    int sum = 0;
    for (int i = 0; i < SCAN_ITEMS; i++) {
        int idx = base + i;
        int v = (idx < n) ? data[idx] : 0;
        sum += v;
        vals[i] = sum;                      // inclusive within thread
    }
    sdata[threadIdx.x] = sum;
    __syncthreads();
    for (int off = 1; off < SCAN_BLOCK; off <<= 1) {
        int t = (threadIdx.x >= off) ? sdata[threadIdx.x - off] : 0;
        __syncthreads();
        sdata[threadIdx.x] += t;
        __syncthreads();
    }
    int thread_off = (threadIdx.x > 0) ? sdata[threadIdx.x - 1] : 0;
    for (int i = 0; i < SCAN_ITEMS; i++) {
        int idx = base + i;
        if (idx < n) data[idx] = vals[i] + thread_off;
    }
    if (block_sums && threadIdx.x == SCAN_BLOCK - 1)
        block_sums[blockIdx.x] = sdata[SCAN_BLOCK - 1];
}

__global__ __launch_bounds__(256)
void scan3_kernel(int* __restrict__ data, int n, const int* __restrict__ block_sums) {
    int idx = blockIdx.x * blockDim.x + threadIdx.x;
    if (idx >= n) return;
    int b = idx / SCAN_TILE;
    if (b > 0) data[idx] += block_sums[b - 1];
}

// ---------------- scatter into CSR buckets ----------------
__global__ __launch_bounds__(256)
void scatter_kernel(const int* __restrict__ row, const int* __restrict__ col,
                    const float* __restrict__ val,
                    int* __restrict__ cursor, int2* __restrict__ packed, int n_edges) {
    int e = blockIdx.x * blockDim.x + threadIdx.x;
    if (e >= n_edges) return;
    int r = row[e];
    int p = atomicAdd(&cursor[r], 1);
    packed[p] = make_int2(col[e], __float_as_int(val[e]));
}

// ---------------- row-stationary reduce ----------------
__global__ __launch_bounds__(256)
void reduce_csr(const float* __restrict__ x, const int2* __restrict__ packed,
                const int* __restrict__ row_start, float* __restrict__ out, int n_nodes) {
    int tid = blockIdx.x * blockDim.x + threadIdx.x;
    int lane = tid & 15;                    // 16 lanes/row, float4 each = 64 feats
    int r = tid >> 4;
    if (r >= n_nodes) return;
    int s = row_start[r];
    int e = row_start[r + 1];
    float4 acc = {0.f, 0.f, 0.f, 0.f};
    for (int i = s; i < e; i++) {
        int2 pe = packed[i];                // broadcast across the 16 lanes
        float v = __int_as_float(pe.y);
        const float4 xv = ((const float4*)(x + (size_t)pe.x * D_FEAT))[lane];
        acc.x += v * xv.x;
        acc.y += v * xv.y;
        acc.z += v * xv.z;
        acc.w += v * xv.w;
    }
    ((float4*)(out + (size_t)r * D_FEAT))[lane] = acc;
}

// ---------------- fallback (round-1 atomic version) ----------------
__global__ __launch_bounds__(256)
void graphconv_scatter(const float* __restrict__ x, const float* __restrict__ edge_vals,
                       const int* __restrict__ row, const int* __restrict__ col,
                       float* __restrict__ out, int n_edges) {
    int tid = blockIdx.x * blockDim.x + threadIdx.x;
    int lane16 = tid & 15;
    int e = tid >> 4;
    if (e >= n_edges) return;
    int r = row[e];
    int c = col[e];
    float v = edge_vals[e];
    const float4* xs = (const float4*)(x + (size_t)c * D_FEAT);
    float4 xv = xs[lane16];
    float* o = out + (size_t)r * D_FEAT + lane16 * 4;
    atomicAdd(o + 0, v * xv.x);
    atomicAdd(o + 1, v * xv.y);
    atomicAdd(o + 2, v * xv.z);
    atomicAdd(o + 3, v * xv.w);
}

extern "C" void kernel_launch(void* const* d_in, const int* in_sizes, int n_in,
                              void* d_out, int out_size, void* d_ws, size_t ws_size,
                              hipStream_t stream) {
    const float* x         = (const float*)d_in[0];
    const float* edge_vals = (const float*)d_in[1];
    const int*   row       = (const int*)d_in[2];
    const int*   col       = (const int*)d_in[3];
    float* out = (float*)d_out;

    const int n_nodes = in_sizes[0] / D_FEAT;
    const int n_edges = in_sizes[1];

    // ---- workspace layout ----
    size_t off = 0;
    auto alloc = [&](size_t bytes) {
        size_t p = off;
        off += (bytes + 15) & ~size_t(15);
        return p;
    };
    size_t o_rowstart = alloc((size_t)(n_nodes + 1) * sizeof(int));
    size_t o_cursor   = alloc((size_t)n_nodes * sizeof(int));
    size_t o_packed   = alloc((size_t)n_edges * sizeof(int2));
    size_t o_bsums    = alloc(4096 * sizeof(int));

    if (off > ws_size) {
        // workspace too small: fall back to pure-atomic version
        hipMemsetAsync(d_out, 0, (size_t)out_size * sizeof(float), stream);
        long long total_threads = (long long)n_edges * 16;
        int grid = (int)((total_threads + 255) / 256);
        graphconv_scatter<<<grid, 256, 0, stream>>>(x, edge_vals, row, col, out, n_edges);
        return;
    }

    char* wsb = (char*)d_ws;
    int*  row_start = (int*)(wsb + o_rowstart);
    int*  cursor    = (int*)(wsb + o_cursor);
    int2* packed    = (int2*)(wsb + o_packed);
    int*  bsums     = (int*)(wsb + o_bsums);

    const int n_scan = n_nodes + 1;
    const int n_scan_blocks = (n_scan + SCAN_TILE - 1) / SCAN_TILE;   // 245 for 500k

    // 1. zero counts
    hipMemsetAsync(row_start, 0, (size_t)n_scan * sizeof(int), stream);

    // 2. histogram (int atomics onto 2 MB, L2-resident)
    hist_kernel<<<(n_edges + 255) / 256, 256, 0, stream>>>(row, row_start, n_edges);

    // 3. inclusive scan -> row_start[i] = start of row i, row_start[N] = E
    scan1_kernel<<<n_scan_blocks, SCAN_BLOCK, 0, stream>>>(row_start, n_scan, bsums);
    scan1_kernel<<<1, SCAN_BLOCK, 0, stream>>>(bsums, n_scan_blocks, nullptr);
    scan3_kernel<<<(n_scan + 255) / 256, 256, 0, stream>>>(row_start, n_scan, bsums);

    // 4. cursor = row starts (working copy for scatter)
    hipMemcpyAsync(cursor, row_start, (size_t)n_nodes * sizeof(int),
                   hipMemcpyDeviceToDevice, stream);

    // 5. scatter (col, val) into row buckets
    scatter_kernel<<<(n_edges + 255) / 256, 256, 0, stream>>>(row, col, edge_vals,
                                                              cursor, packed, n_edges);

    // 6. row-stationary reduce, plain stores (writes every output element)
    long long rthreads = (long long)n_nodes * 16;
    reduce_csr<<<(int)((rthreads + 255) / 256), 256, 0, stream>>>(x, packed, row_start,
                                                                  out, n_nodes);
}